// Round 8
// baseline (425.466 us; speedup 1.0000x reference)
//
#include <hip/hip_runtime.h>

#define P_PTS 131072
#define CDIM  512
#define MCAP  1024
#define TLEN  262144
#define PORIG 163840

typedef unsigned short u16;
typedef unsigned char  u8;
typedef __attribute__((ext_vector_type(8))) short short8;
typedef __attribute__((ext_vector_type(4))) float f32x4;
typedef __attribute__((ext_vector_type(8))) int int8v;
typedef __attribute__((ext_vector_type(4))) int int4v;

union V32 { int8v v8; int4v v4[2]; };   // 32-byte operand: 2x16B loads, 1 MFMA reg tuple

__device__ __forceinline__ u16 f2bf(float f) {
    unsigned u = __float_as_uint(f);
    unsigned r = (u + 0x7FFFu + ((u >> 16) & 1u)) >> 16;
    return (u16)r;
}
// OCP e4m3 decode: normals AND subnormals via f32-subnormal trick
__device__ __forceinline__ float d_e4m3(unsigned x) {
    float f = __uint_as_float((x & 0x7Fu) << 20) * 0x1p120f;
    return __uint_as_float(__float_as_uint(f) | ((x & 0x80u) << 24));
}
__device__ __forceinline__ void ld16(const void* g, void* l) {
    __builtin_amdgcn_global_load_lds(
        (const __attribute__((address_space(1))) void*)g,
        (__attribute__((address_space(3))) void*)l, 16, 0, 0);
}

// feats8 layout (MFMA-A fragment order + bank swizzle):
//   chunk(rowblk=row>>4, kk=c>>7) of 2048 B; within-chunk linear offset
//   o = ((c>>5)&3)*512 + (row&15)*32 + (c&31); STORED at o ^ (((o>>8)&7)<<4).
//   Conflict-free ds_read_b128 (verified R7: SQ_LDS_BANK_CONFLICT = 0).

// ---- fused: gather+normalize (blocks 0..32767, swizzled feats8 via LDS
//      transpose), cap cast bf16 + ptom scatter (32768..33279), lse_sum zero
//      (33280..33791), B pre-swizzle (33792..33919)
__global__ __launch_bounds__(256) void gather_prep(
    const float* __restrict__ adapter, const int* __restrict__ v2p,
    const float* __restrict__ cap, const int* __restrict__ oidx,
    u8* __restrict__ feats8, u16* __restrict__ capb, u8* __restrict__ Bswz,
    int* __restrict__ ptom, float* __restrict__ lse_sum) {
    __shared__ __align__(16) u8 sm[4 * 544];
    int b = blockIdx.x, tid = threadIdx.x;
    if (b < 32768) {
        int w = tid >> 6, lane = tid & 63;
        int p = b * 4 + w;
        int vrow = v2p[p];
        const float4* src = (const float4*)(adapter + (size_t)vrow * CDIM);
        float4 x0 = src[lane * 2];
        float4 x1 = src[lane * 2 + 1];
        float ss = x0.x*x0.x + x0.y*x0.y + x0.z*x0.z + x0.w*x0.w
                 + x1.x*x1.x + x1.y*x1.y + x1.z*x1.z + x1.w*x1.w;
        #pragma unroll
        for (int off = 32; off >= 1; off >>= 1) ss += __shfl_xor(ss, off, 64);
        float inv = 1.0f / fmaxf(sqrtf(ss), 1e-12f);
        int lo = __builtin_amdgcn_cvt_pk_fp8_f32(x0.x*inv, x0.y*inv, 0, false);
        lo = __builtin_amdgcn_cvt_pk_fp8_f32(x0.z*inv, x0.w*inv, lo, true);
        int hi = __builtin_amdgcn_cvt_pk_fp8_f32(x1.x*inv, x1.y*inv, 0, false);
        hi = __builtin_amdgcn_cvt_pk_fp8_f32(x1.z*inv, x1.w*inv, hi, true);
        uint2 wv; wv.x = (unsigned)lo; wv.y = (unsigned)hi;
        *(uint2*)(sm + w * 544 + lane * 8) = wv;     // row w, bytes lane*8..+8
        __syncthreads();
        // write out in fragment order (+ bank swizzle): 16 chunks (kk,q)
        int chunk = tid >> 4, inner = tid & 15;
        int kk = chunk >> 2, q = chunk & 3, rr = inner >> 2;
        uint2 v = *(const uint2*)(sm + rr * 544 + kk * 128 + q * 32 + (inner & 3) * 8);
        int o = q * 512 + (b & 3) * 128 + inner * 8;
        o ^= ((o >> 8) & 7) << 4;                    // bank swizzle
        *(uint2*)(feats8 + (size_t)(b >> 2) * 8192 + kk * 2048 + o) = v;
    } else if (b < 33280) {
        int t = (b - 32768) * 256 + tid;       // [0, 131072)
        int i = t * 4;
        float4 v = *(const float4*)(cap + i);
        u16* o = capb + i;
        o[0] = f2bf(v.x); o[1] = f2bf(v.y); o[2] = f2bf(v.z); o[3] = f2bf(v.w);
        atomicMax(&ptom[oidx[t]], t);          // last-write-wins == max (t increasing)
    } else if (b < 33792) {
        int j = (b - 33280) * 256 + tid;       // [0, 131072)
        lse_sum[j] = 0.0f;
    } else {
        // B pre-swizzle into MFMA fragment order: granule g2 (16 B) ->
        // c=g2&1, lane=(g2>>1)&63, j=(g2>>7)&3, kk=(g2>>9)&3, wn=(g2>>11)&1, c0=g2>>12
        int g2 = (b - 33792) * 256 + tid;      // [0, 32768)
        int c    = g2 & 1;
        int lane = (g2 >> 1) & 63;
        int j    = (g2 >> 7) & 3;
        int kk   = (g2 >> 9) & 3;
        int wn   = (g2 >> 11) & 1;
        int c0   = g2 >> 12;
        int col  = c0 * 128 + wn * 64 + j * 16 + (lane & 15);
        int kb   = kk * 128 + (lane >> 4) * 32 + c * 16;
        const float* s = cap + (size_t)col * CDIM + kb;
        unsigned w4[4];
        #pragma unroll
        for (int u = 0; u < 4; ++u) {
            int p = __builtin_amdgcn_cvt_pk_fp8_f32(s[u*4+0], s[u*4+1], 0, false);
            p = __builtin_amdgcn_cvt_pk_fp8_f32(s[u*4+2], s[u*4+3], p, true);
            w4[u] = (unsigned)p;
        }
        *(uint4*)(Bswz + (size_t)g2 * 16) = *(uint4*)w4;
    }
}

// ---- heavy GEMM: MX-fp8 K=128 MFMA.
//      Block = 128 rows x ALL 1024 cols (A-traffic 512->64 MB vs 128x128
//      tiling). A-tile (64 KB, swizzled fragment order) staged into LDS ONCE
//      via global_load_lds (wave-uniform dest); ONE __syncthreads total; then
//      8 c0-tiles computed completely barrier-free: B via V32 direct loads
//      (pre-swizzled, no unpack movs), A via conflict-free swizzled
//      ds_read_b128. Per-lane exp partials (psum) accumulate across c0 with
//      ONE cross-lane reduce at end; atomicAdd combines the two column-half
//      waves per row (race-free, verified R7 path). No launch-bounds clamp
//      (R6's (256,4) caused 557 MB spill). Tail blocks (>=1024) do make_rows.
__global__ __launch_bounds__(256) void lse_gemm(
    const u8* __restrict__ feats8, const u8* __restrict__ Bswz,
    const float* __restrict__ lsc, float* __restrict__ lse_sum,
    const int* __restrict__ ctpm, const int* __restrict__ ptom,
    unsigned* __restrict__ rows) {
    if (blockIdx.x >= 1024) {                  // make_rows tail
        int t = (blockIdx.x - 1024) * 256 + threadIdx.x;
        int g = ptom[ctpm[t]];
        rows[t] = (g < 0) ? ((unsigned)(g + P_PTS) | 0x80000000u) : (unsigned)g;
        return;
    }
    __shared__ __align__(16) u8 As[65536];
    const int tid  = threadIdx.x;
    const int wave = tid >> 6;
    const int lane = tid & 63;
    const int rt   = blockIdx.x;               // row-tile 0..1023
    const int row0 = rt * 128;
    const int wm   = (wave >> 1) * 64;
    const int wn1  = (wave & 1);
    const float sf = __expf(lsc[0]);

    // ---- stage whole 64 KB A-tile once: wave w stages rowblks 2w, 2w+1
    //      (16 x 1 KB pieces; LDS dest wave-uniform, HW adds lane*16) ----
    {
        const u8* src = feats8 + ((size_t)rt * 8 + wave * 2) * 8192 + lane * 16;
        u8* dst = As + wave * 2 * 8192;
        #pragma unroll
        for (int u = 0; u < 16; ++u)
            ld16(src + (size_t)(u >> 3) * 8192 + (u & 7) * 1024,
                 dst + (u >> 3) * 8192 + (u & 7) * 1024);
    }
    __syncthreads();                           // single barrier in the kernel

    // swizzled A-frag read offsets (verified conflict-free in R7)
    const int sA = (lane * 32) ^ (((lane >> 3) & 7) << 4);
    // A frag (i,kk): As + ((wave>>1)*4 + i)*8192 + kk*2048 + sA (hi at ^16)
    const u8* rA  = As + (size_t)((wave >> 1) * 4) * 8192 + sA;
    const u8* rAx = As + (size_t)((wave >> 1) * 4) * 8192 + (sA ^ 16);
    // B frag (c0,kk,j): Bswz + ((c0*2+wn1)*16 + kk*4 + j)*2048 + lane*32 (+16)
    const u8* bwBase = Bswz + (size_t)wn1 * 32768 + lane * 32;

    float psum[4][4];
    #pragma unroll
    for (int i = 0; i < 4; ++i)
        #pragma unroll
        for (int r = 0; r < 4; ++r) psum[i][r] = 0.f;

    #pragma unroll 1
    for (int c0 = 0; c0 < 8; ++c0) {
        const u8* bw = bwBase + (size_t)c0 * 65536;
        f32x4 acc[4][4] = {};
        #pragma unroll
        for (int kk = 0; kk < 4; ++kk) {
            V32 bv[4];
            #pragma unroll
            for (int j = 0; j < 4; ++j) {
                bv[j].v4[0] = *(const int4v*)(bw + kk * 8192 + j * 2048);
                bv[j].v4[1] = *(const int4v*)(bw + kk * 8192 + j * 2048 + 16);
            }
            __builtin_amdgcn_s_setprio(1);
            #pragma unroll
            for (int i = 0; i < 4; ++i) {
                V32 af;
                af.v4[0] = *(const int4v*)(rA  + i * 8192 + kk * 2048);
                af.v4[1] = *(const int4v*)(rAx + i * 8192 + kk * 2048);
                #pragma unroll
                for (int j = 0; j < 4; ++j)
                    acc[i][j] = __builtin_amdgcn_mfma_scale_f32_16x16x128_f8f6f4(
                        af.v8, bv[j].v8, acc[i][j], 0, 0, 0, 127, 0, 127);
            }
            __builtin_amdgcn_s_setprio(0);
        }
        // per-c0 epilogue: exp into per-lane partials (VALU overlaps next
        // c0's B loads; no cross-lane traffic here)
        #pragma unroll
        for (int i = 0; i < 4; ++i)
            #pragma unroll
            for (int j = 0; j < 4; ++j)
                #pragma unroll
                for (int r = 0; r < 4; ++r)
                    psum[i][r] += __expf(acc[i][j][r] * sf - sf);
    }

    // single cross-lane reduce (within 16-lane column groups), then combine
    // the two wn1 waves per row via atomicAdd (lse_sum pre-zeroed)
    const int m = lane & 15;
    const int q = lane >> 4;
    #pragma unroll
    for (int i = 0; i < 4; ++i)
        #pragma unroll
        for (int r = 0; r < 4; ++r) {
            float v = psum[i][r];
            #pragma unroll
            for (int off = 8; off >= 1; off >>= 1) v += __shfl_xor(v, off, 64);
            if (m == 0)
                atomicAdd(&lse_sum[row0 + wm + i * 16 + q * 4 + r], v);
        }
}

__device__ __forceinline__ int lower_bound(const int* __restrict__ a, int n, int key) {
    int lo = 0, hi = n;
    while (lo < hi) { int mid = (lo + hi) >> 1; if (a[mid] < key) lo = mid + 1; else hi = mid; }
    return lo;
}

// ---- per-segment: Fb[s] = sum feats rows (bf16), L[s] = sum log lse_sum, counts.
//      feats8 reads apply the same store-side XOR swizzle; lane->channel
//      ownership unchanged (chb as before). ----
__global__ __launch_bounds__(1024) void seg_reduce(
    const u8* __restrict__ feats8, const float* __restrict__ lse_sum,
    const unsigned* __restrict__ rows, const int* __restrict__ seg,
    const float* __restrict__ lsc,
    u16* __restrict__ Fb, float* __restrict__ Lout, float* __restrict__ realn) {
    int s = blockIdx.x;
    int tid = threadIdx.x, wave = tid >> 6, lane = tid & 63;
    int start = lower_bound(seg, TLEN, s);
    int end   = lower_bound(seg, TLEN, s + 1);
    const int lbase  = ((lane >> 2) & 3) * 512 + (lane & 3) * 8;
    const int lchunk = (lane >> 4) * 2048;
    const int chb    = (lane >> 4) * 128 + ((lane >> 2) & 3) * 32 + (lane & 3) * 8;
    float a[8] = {0,0,0,0,0,0,0,0};
    float Lacc = 0.f; int inv = 0;
    int r = start + wave;
    for (; r + 16 < end; r += 32) {
        unsigned p0 = rows[r], p1 = rows[r + 16];
        int r0 = (int)(p0 & 0x7FFFFFFFu), r1 = (int)(p1 & 0x7FFFFFFFu);
        int o0 = lbase + (r0 & 15) * 32; o0 ^= ((o0 >> 8) & 7) << 4;
        int o1 = lbase + (r1 & 15) * 32; o1 ^= ((o1 >> 8) & 7) << 4;
        uint2 v0 = *(const uint2*)(feats8 + (size_t)(r0 >> 4) * 8192 + lchunk + o0);
        uint2 v1 = *(const uint2*)(feats8 + (size_t)(r1 >> 4) * 8192 + lchunk + o1);
        if (lane == 0) {
            inv += (int)(p0 >> 31) + (int)(p1 >> 31);
            Lacc += __logf(lse_sum[r0]) + __logf(lse_sum[r1]);
        }
        a[0] += d_e4m3(v0.x);       a[1] += d_e4m3(v0.x >> 8);
        a[2] += d_e4m3(v0.x >> 16); a[3] += d_e4m3(v0.x >> 24);
        a[4] += d_e4m3(v0.y);       a[5] += d_e4m3(v0.y >> 8);
        a[6] += d_e4m3(v0.y >> 16); a[7] += d_e4m3(v0.y >> 24);
        a[0] += d_e4m3(v1.x);       a[1] += d_e4m3(v1.x >> 8);
        a[2] += d_e4m3(v1.x >> 16); a[3] += d_e4m3(v1.x >> 24);
        a[4] += d_e4m3(v1.y);       a[5] += d_e4m3(v1.y >> 8);
        a[6] += d_e4m3(v1.y >> 16); a[7] += d_e4m3(v1.y >> 24);
    }
    if (r < end) {
        unsigned p0 = rows[r];
        int r0 = (int)(p0 & 0x7FFFFFFFu);
        int o0 = lbase + (r0 & 15) * 32; o0 ^= ((o0 >> 8) & 7) << 4;
        uint2 v0 = *(const uint2*)(feats8 + (size_t)(r0 >> 4) * 8192 + lchunk + o0);
        if (lane == 0) { inv += (int)(p0 >> 31); Lacc += __logf(lse_sum[r0]); }
        a[0] += d_e4m3(v0.x);       a[1] += d_e4m3(v0.x >> 8);
        a[2] += d_e4m3(v0.x >> 16); a[3] += d_e4m3(v0.x >> 24);
        a[4] += d_e4m3(v0.y);       a[5] += d_e4m3(v0.y >> 8);
        a[6] += d_e4m3(v0.y >> 16); a[7] += d_e4m3(v0.y >> 24);
    }
    __shared__ float pF[16][512];
    __shared__ float pL[16];
    __shared__ int   pI[16];
    #pragma unroll
    for (int u = 0; u < 8; ++u) pF[wave][chb + u] = a[u];
    if (lane == 0) { pL[wave] = Lacc; pI[wave] = inv; }
    __syncthreads();
    if (tid < 512) {
        float f = 0.f;
        #pragma unroll
        for (int w = 0; w < 16; ++w) f += pF[w][tid];
        Fb[(size_t)s * CDIM + tid] = f2bf(f);
    }
    if (tid == 0) {
        float cnt = (float)(end - start);
        float Ls = 0.f; int ninv = 0;
        #pragma unroll
        for (int w = 0; w < 16; ++w) { Ls += pL[w]; ninv += pI[w]; }
        realn[s] = cnt - (float)ninv;
        Lout[s] = Ls + __expf(lsc[0]) * cnt;   // each lse = sf + log(sum)
    }
}

// ---- pooled[s,m] = (sf*Fb[s].capb[m] - L[s]) * (1/real or 0); 64x64 bf16 MFMA
//      NO LDS, NO BARRIERS: fragments loaded direct from row-major Fb/capb
//      (both 1 MB, L2-resident). ----
__global__ __launch_bounds__(256) void pooled_gemm(
    const u16* __restrict__ Fb, const u16* __restrict__ capb,
    const float* __restrict__ Lout, const float* __restrict__ realn,
    const float* __restrict__ lsc, float* __restrict__ out) {
    const int tid  = threadIdx.x;
    const int wave = tid >> 6;
    const int lane = tid & 63;
    const int col0 = blockIdx.x * 64;   // captions
    const int row0 = blockIdx.y * 64;   // segments
    const int wm = (wave >> 1) * 32;
    const int wn = (wave & 1) * 32;
    const float sf = __expf(lsc[0]);
    f32x4 acc[2][2] = {};
    const int mrow = lane & 15;
    const int quad = lane >> 4;
    // fragment for 16x16x32 bf16: lane (mrow,quad) holds row[k0+quad*8 .. +8]
    const u16* gA = Fb   + (size_t)(row0 + wm + mrow) * CDIM + quad * 8;
    const u16* gB = capb + (size_t)(col0 + wn + mrow) * CDIM + quad * 8;
    #pragma unroll
    for (int k0 = 0; k0 < CDIM; k0 += 32) {
        short8 af[2], bfr[2];
        #pragma unroll
        for (int i = 0; i < 2; ++i)
            af[i]  = *(const short8*)(gA + (size_t)(i * 16) * CDIM + k0);
        #pragma unroll
        for (int j = 0; j < 2; ++j)
            bfr[j] = *(const short8*)(gB + (size_t)(j * 16) * CDIM + k0);
        #pragma unroll
        for (int i = 0; i < 2; ++i)
            #pragma unroll
            for (int j = 0; j < 2; ++j)
                acc[i][j] = __builtin_amdgcn_mfma_f32_16x16x32_bf16(
                    af[i], bfr[j], acc[i][j], 0, 0, 0);
    }
    #pragma unroll
    for (int i = 0; i < 2; ++i) {
        #pragma unroll
        for (int r = 0; r < 4; ++r) {
            int s = row0 + wm + i * 16 + quad * 4 + r;
            float rn = realn[s];
            float dn = rn > 0.f ? 1.0f / rn : 0.0f;
            float L = Lout[s];
            #pragma unroll
            for (int j = 0; j < 2; ++j) {
                int mc = col0 + wn + j * 16 + mrow;
                out[(size_t)s * MCAP + mc] = (sf * acc[i][j][r] - L) * dn;
            }
        }
    }
    if (col0 == 0 && tid < 64) {
        int s = row0 + tid;
        float rv = realn[s];
        out[MCAP * MCAP + s] = rv;
        out[MCAP * MCAP + MCAP + s] = (rv > 0.f) ? 1.0f : 0.0f;
    }
}

extern "C" void kernel_launch(void* const* d_in, const int* in_sizes, int n_in,
                              void* d_out, int out_size, void* d_ws, size_t ws_size,
                              hipStream_t stream) {
    const float* adapter = (const float*)d_in[0];
    const float* cap     = (const float*)d_in[1];
    const float* lsc     = (const float*)d_in[2];
    const int*   v2p     = (const int*)d_in[3];
    const int*   oidx    = (const int*)d_in[4];
    const int*   ctpm    = (const int*)d_in[5];
    const int*   seg     = (const int*)d_in[6];
    float* out = (float*)d_out;

    char* ws = (char*)d_ws;
    u8*       feats8  = (u8*)(ws);                                // 67,108,864 B
    u16*      capb    = (u16*)(ws + 67108864);                    //  1,048,576 B
    u8*       Bswz    = (u8*)(ws + 68157440);                     //    524,288 B
    float*    lse_sum = (float*)(ws + 68681728);                  //    524,288 B
    int*      ptom    = (int*)(ws + 69206016);                    //    655,360 B
    unsigned* rows    = (unsigned*)(ws + 69861376);               //  1,048,576 B
    u16*      Fb      = (u16*)(ws + 70909952);                    //  1,048,576 B
    float*    Lout    = (float*)(ws + 71958528);                  //      4,096 B
    float*    realn   = (float*)(ws + 71962624);                  //      4,096 B

    hipMemsetAsync(ptom, 0xFF, (size_t)PORIG * 4, stream);        // -1

    gather_prep<<<33920, 256, 0, stream>>>(adapter, v2p, cap, oidx,
                                           feats8, capb, Bswz, ptom, lse_sum);
    lse_gemm<<<1024 + TLEN / 256, 256, 0, stream>>>(feats8, Bswz, lsc, lse_sum,
                                                    ctpm, ptom, rows);
    seg_reduce<<<MCAP, 1024, 0, stream>>>(feats8, lse_sum, rows, seg, lsc, Fb, Lout, realn);
    pooled_gemm<<<dim3(MCAP / 64, MCAP / 64), 256, 0, stream>>>(Fb, capb, Lout, realn, lsc, out);
}

// Round 9
// 410.043 us; speedup vs baseline: 1.0376x; 1.0376x over previous
//
#include <hip/hip_runtime.h>

#define P_PTS 131072
#define CDIM  512
#define MCAP  1024
#define TLEN  262144
#define PORIG 163840

typedef unsigned short u16;
typedef unsigned char  u8;
typedef __attribute__((ext_vector_type(8))) short short8;
typedef __attribute__((ext_vector_type(4))) float f32x4;
typedef __attribute__((ext_vector_type(8))) int int8v;
typedef __attribute__((ext_vector_type(4))) int int4v;

union V32 { int8v v8; int4v v4[2]; };   // 32-byte operand: 2x16B loads, 1 MFMA reg tuple

__device__ __forceinline__ u16 f2bf(float f) {
    unsigned u = __float_as_uint(f);
    unsigned r = (u + 0x7FFFu + ((u >> 16) & 1u)) >> 16;
    return (u16)r;
}
// OCP e4m3 decode: normals AND subnormals via f32-subnormal trick
__device__ __forceinline__ float d_e4m3(unsigned x) {
    float f = __uint_as_float((x & 0x7Fu) << 20) * 0x1p120f;
    return __uint_as_float(__float_as_uint(f) | ((x & 0x80u) << 24));
}
__device__ __forceinline__ void ld16(const void* g, void* l) {
    __builtin_amdgcn_global_load_lds(
        (const __attribute__((address_space(1))) void*)g,
        (__attribute__((address_space(3))) void*)l, 16, 0, 0);
}

// feats8 layout (MFMA-A fragment order + bank swizzle):
//   chunk(rowblk=row>>4, kk=c>>7) of 2048 B; within-chunk linear offset
//   o = ((c>>5)&3)*512 + (row&15)*32 + (c&31); STORED at o ^ (((o>>8)&7)<<4).
//   Conflict-free ds_read_b128 (verified R7: SQ_LDS_BANK_CONFLICT = 0).

// ---- fused: gather+normalize (blocks 0..32767, swizzled feats8 via LDS
//      transpose), cap cast bf16 + ptom scatter (32768..33279), lse_sum zero
//      (33280..33791), B pre-swizzle (33792..33919)
__global__ __launch_bounds__(256) void gather_prep(
    const float* __restrict__ adapter, const int* __restrict__ v2p,
    const float* __restrict__ cap, const int* __restrict__ oidx,
    u8* __restrict__ feats8, u16* __restrict__ capb, u8* __restrict__ Bswz,
    int* __restrict__ ptom, float* __restrict__ lse_sum) {
    __shared__ __align__(16) u8 sm[4 * 544];
    int b = blockIdx.x, tid = threadIdx.x;
    if (b < 32768) {
        int w = tid >> 6, lane = tid & 63;
        int p = b * 4 + w;
        int vrow = v2p[p];
        const float4* src = (const float4*)(adapter + (size_t)vrow * CDIM);
        float4 x0 = src[lane * 2];
        float4 x1 = src[lane * 2 + 1];
        float ss = x0.x*x0.x + x0.y*x0.y + x0.z*x0.z + x0.w*x0.w
                 + x1.x*x1.x + x1.y*x1.y + x1.z*x1.z + x1.w*x1.w;
        #pragma unroll
        for (int off = 32; off >= 1; off >>= 1) ss += __shfl_xor(ss, off, 64);
        float inv = 1.0f / fmaxf(sqrtf(ss), 1e-12f);
        int lo = __builtin_amdgcn_cvt_pk_fp8_f32(x0.x*inv, x0.y*inv, 0, false);
        lo = __builtin_amdgcn_cvt_pk_fp8_f32(x0.z*inv, x0.w*inv, lo, true);
        int hi = __builtin_amdgcn_cvt_pk_fp8_f32(x1.x*inv, x1.y*inv, 0, false);
        hi = __builtin_amdgcn_cvt_pk_fp8_f32(x1.z*inv, x1.w*inv, hi, true);
        uint2 wv; wv.x = (unsigned)lo; wv.y = (unsigned)hi;
        *(uint2*)(sm + w * 544 + lane * 8) = wv;     // row w, bytes lane*8..+8
        __syncthreads();
        // write out in fragment order (+ bank swizzle): 16 chunks (kk,q)
        int chunk = tid >> 4, inner = tid & 15;
        int kk = chunk >> 2, q = chunk & 3, rr = inner >> 2;
        uint2 v = *(const uint2*)(sm + rr * 544 + kk * 128 + q * 32 + (inner & 3) * 8);
        int o = q * 512 + (b & 3) * 128 + inner * 8;
        o ^= ((o >> 8) & 7) << 4;                    // bank swizzle
        *(uint2*)(feats8 + (size_t)(b >> 2) * 8192 + kk * 2048 + o) = v;
    } else if (b < 33280) {
        int t = (b - 32768) * 256 + tid;       // [0, 131072)
        int i = t * 4;
        float4 v = *(const float4*)(cap + i);
        u16* o = capb + i;
        o[0] = f2bf(v.x); o[1] = f2bf(v.y); o[2] = f2bf(v.z); o[3] = f2bf(v.w);
        atomicMax(&ptom[oidx[t]], t);          // last-write-wins == max (t increasing)
    } else if (b < 33792) {
        int j = (b - 33280) * 256 + tid;       // [0, 131072)
        lse_sum[j] = 0.0f;
    } else {
        // B pre-swizzle into MFMA fragment order: granule g2 (16 B) ->
        // c=g2&1, lane=(g2>>1)&63, j=(g2>>7)&3, kk=(g2>>9)&3, wn=(g2>>11)&1, c0=g2>>12
        int g2 = (b - 33792) * 256 + tid;      // [0, 32768)
        int c    = g2 & 1;
        int lane = (g2 >> 1) & 63;
        int j    = (g2 >> 7) & 3;
        int kk   = (g2 >> 9) & 3;
        int wn   = (g2 >> 11) & 1;
        int c0   = g2 >> 12;
        int col  = c0 * 128 + wn * 64 + j * 16 + (lane & 15);
        int kb   = kk * 128 + (lane >> 4) * 32 + c * 16;
        const float* s = cap + (size_t)col * CDIM + kb;
        unsigned w4[4];
        #pragma unroll
        for (int u = 0; u < 4; ++u) {
            int p = __builtin_amdgcn_cvt_pk_fp8_f32(s[u*4+0], s[u*4+1], 0, false);
            p = __builtin_amdgcn_cvt_pk_fp8_f32(s[u*4+2], s[u*4+3], p, true);
            w4[u] = (unsigned)p;
        }
        *(uint4*)(Bswz + (size_t)g2 * 16) = *(uint4*)w4;
    }
}

// ---- heavy GEMM: MX-fp8 K=128 MFMA.
//      Block = 64 rows x ALL 1024 cols. A-tile 32 KB staged ONCE (one
//      barrier), then 8 c0-tiles barrier-free. 32 KB LDS + ~110 VGPR ->
//      ~4 blocks/CU resident = 4 waves/SIMD (vs R8's 2): independent blocks
//      at different phases cover each other's B-load stalls (the R8 limiter:
//      ~300-600cy exposed L2 latency per c0 with only 2 lockstep waves).
//      B via V32 direct loads (pre-swizzled); A via conflict-free swizzled
//      ds_read_b128; per-lane psum, one reduce + atomicAdd at end.
//      Tail blocks (>=2048) do make_rows.
__global__ __launch_bounds__(256) void lse_gemm(
    const u8* __restrict__ feats8, const u8* __restrict__ Bswz,
    const float* __restrict__ lsc, float* __restrict__ lse_sum,
    const int* __restrict__ ctpm, const int* __restrict__ ptom,
    unsigned* __restrict__ rows) {
    if (blockIdx.x >= 2048) {                  // make_rows tail
        int t = (blockIdx.x - 2048) * 256 + threadIdx.x;
        int g = ptom[ctpm[t]];
        rows[t] = (g < 0) ? ((unsigned)(g + P_PTS) | 0x80000000u) : (unsigned)g;
        return;
    }
    __shared__ __align__(16) u8 As[32768];
    const int tid  = threadIdx.x;
    const int wave = tid >> 6;
    const int lane = tid & 63;
    const int rt   = blockIdx.x;               // 64-row tile 0..2047
    const int row0 = rt * 64;
    const int wm   = (wave >> 1) * 32;
    const int wn1  = (wave & 1);
    const float sf = __expf(lsc[0]);

    // ---- stage 32 KB A-tile once: wave w stages rowblk w (8 x 1 KB;
    //      LDS dest wave-uniform, HW adds lane*16) ----
    {
        const u8* src = feats8 + ((size_t)rt * 4 + wave) * 8192 + lane * 16;
        u8* dst = As + wave * 8192;
        #pragma unroll
        for (int u = 0; u < 8; ++u)
            ld16(src + u * 1024, dst + u * 1024);
    }
    __syncthreads();                           // single barrier in the kernel

    // swizzled A-frag read offsets (verified conflict-free in R7)
    const int sA = (lane * 32) ^ (((lane >> 3) & 7) << 4);
    // A frag (i,kk): As + ((wave>>1)*2 + i)*8192 + kk*2048 + sA (hi at ^16)
    const u8* rA  = As + (size_t)((wave >> 1) * 2) * 8192 + sA;
    const u8* rAx = As + (size_t)((wave >> 1) * 2) * 8192 + (sA ^ 16);
    // B frag (c0,kk,j): Bswz + ((c0*2+wn1)*16 + kk*4 + j)*2048 + lane*32 (+16)
    const u8* bwBase = Bswz + (size_t)wn1 * 32768 + lane * 32;

    float psum[2][4];
    #pragma unroll
    for (int i = 0; i < 2; ++i)
        #pragma unroll
        for (int r = 0; r < 4; ++r) psum[i][r] = 0.f;

    #pragma unroll 1
    for (int c0 = 0; c0 < 8; ++c0) {
        const u8* bw = bwBase + (size_t)c0 * 65536;
        f32x4 acc[2][4] = {};
        #pragma unroll
        for (int kk = 0; kk < 4; ++kk) {
            V32 bv[4];
            #pragma unroll
            for (int j = 0; j < 4; ++j) {
                bv[j].v4[0] = *(const int4v*)(bw + kk * 8192 + j * 2048);
                bv[j].v4[1] = *(const int4v*)(bw + kk * 8192 + j * 2048 + 16);
            }
            __builtin_amdgcn_s_setprio(1);
            #pragma unroll
            for (int i = 0; i < 2; ++i) {
                V32 af;
                af.v4[0] = *(const int4v*)(rA  + i * 8192 + kk * 2048);
                af.v4[1] = *(const int4v*)(rAx + i * 8192 + kk * 2048);
                #pragma unroll
                for (int j = 0; j < 4; ++j)
                    acc[i][j] = __builtin_amdgcn_mfma_scale_f32_16x16x128_f8f6f4(
                        af.v8, bv[j].v8, acc[i][j], 0, 0, 0, 127, 0, 127);
            }
            __builtin_amdgcn_s_setprio(0);
        }
        // per-c0 epilogue: exp into per-lane partials (VALU overlaps other
        // resident waves' loads/MFMAs; no cross-lane traffic here)
        #pragma unroll
        for (int i = 0; i < 2; ++i)
            #pragma unroll
            for (int j = 0; j < 4; ++j)
                #pragma unroll
                for (int r = 0; r < 4; ++r)
                    psum[i][r] += __expf(acc[i][j][r] * sf - sf);
    }

    // single cross-lane reduce (within 16-lane column groups), then combine
    // the two wn1 waves per row via atomicAdd (lse_sum pre-zeroed)
    const int m = lane & 15;
    const int q = lane >> 4;
    #pragma unroll
    for (int i = 0; i < 2; ++i)
        #pragma unroll
        for (int r = 0; r < 4; ++r) {
            float v = psum[i][r];
            #pragma unroll
            for (int off = 8; off >= 1; off >>= 1) v += __shfl_xor(v, off, 64);
            if (m == 0)
                atomicAdd(&lse_sum[row0 + wm + i * 16 + q * 4 + r], v);
        }
}

__device__ __forceinline__ int lower_bound(const int* __restrict__ a, int n, int key) {
    int lo = 0, hi = n;
    while (lo < hi) { int mid = (lo + hi) >> 1; if (a[mid] < key) lo = mid + 1; else hi = mid; }
    return lo;
}

// ---- per-segment: Fb[s] = sum feats rows (bf16), L[s] = sum log lse_sum, counts.
//      feats8 reads apply the same store-side XOR swizzle; lane->channel
//      ownership unchanged (chb as before). ----
__global__ __launch_bounds__(1024) void seg_reduce(
    const u8* __restrict__ feats8, const float* __restrict__ lse_sum,
    const unsigned* __restrict__ rows, const int* __restrict__ seg,
    const float* __restrict__ lsc,
    u16* __restrict__ Fb, float* __restrict__ Lout, float* __restrict__ realn) {
    int s = blockIdx.x;
    int tid = threadIdx.x, wave = tid >> 6, lane = tid & 63;
    int start = lower_bound(seg, TLEN, s);
    int end   = lower_bound(seg, TLEN, s + 1);
    const int lbase  = ((lane >> 2) & 3) * 512 + (lane & 3) * 8;
    const int lchunk = (lane >> 4) * 2048;
    const int chb    = (lane >> 4) * 128 + ((lane >> 2) & 3) * 32 + (lane & 3) * 8;
    float a[8] = {0,0,0,0,0,0,0,0};
    float Lacc = 0.f; int inv = 0;
    int r = start + wave;
    for (; r + 16 < end; r += 32) {
        unsigned p0 = rows[r], p1 = rows[r + 16];
        int r0 = (int)(p0 & 0x7FFFFFFFu), r1 = (int)(p1 & 0x7FFFFFFFu);
        int o0 = lbase + (r0 & 15) * 32; o0 ^= ((o0 >> 8) & 7) << 4;
        int o1 = lbase + (r1 & 15) * 32; o1 ^= ((o1 >> 8) & 7) << 4;
        uint2 v0 = *(const uint2*)(feats8 + (size_t)(r0 >> 4) * 8192 + lchunk + o0);
        uint2 v1 = *(const uint2*)(feats8 + (size_t)(r1 >> 4) * 8192 + lchunk + o1);
        if (lane == 0) {
            inv += (int)(p0 >> 31) + (int)(p1 >> 31);
            Lacc += __logf(lse_sum[r0]) + __logf(lse_sum[r1]);
        }
        a[0] += d_e4m3(v0.x);       a[1] += d_e4m3(v0.x >> 8);
        a[2] += d_e4m3(v0.x >> 16); a[3] += d_e4m3(v0.x >> 24);
        a[4] += d_e4m3(v0.y);       a[5] += d_e4m3(v0.y >> 8);
        a[6] += d_e4m3(v0.y >> 16); a[7] += d_e4m3(v0.y >> 24);
        a[0] += d_e4m3(v1.x);       a[1] += d_e4m3(v1.x >> 8);
        a[2] += d_e4m3(v1.x >> 16); a[3] += d_e4m3(v1.x >> 24);
        a[4] += d_e4m3(v1.y);       a[5] += d_e4m3(v1.y >> 8);
        a[6] += d_e4m3(v1.y >> 16); a[7] += d_e4m3(v1.y >> 24);
    }
    if (r < end) {
        unsigned p0 = rows[r];
        int r0 = (int)(p0 & 0x7FFFFFFFu);
        int o0 = lbase + (r0 & 15) * 32; o0 ^= ((o0 >> 8) & 7) << 4;
        uint2 v0 = *(const uint2*)(feats8 + (size_t)(r0 >> 4) * 8192 + lchunk + o0);
        if (lane == 0) { inv += (int)(p0 >> 31); Lacc += __logf(lse_sum[r0]); }
        a[0] += d_e4m3(v0.x);       a[1] += d_e4m3(v0.x >> 8);
        a[2] += d_e4m3(v0.x >> 16); a[3] += d_e4m3(v0.x >> 24);
        a[4] += d_e4m3(v0.y);       a[5] += d_e4m3(v0.y >> 8);
        a[6] += d_e4m3(v0.y >> 16); a[7] += d_e4m3(v0.y >> 24);
    }
    __shared__ float pF[16][512];
    __shared__ float pL[16];
    __shared__ int   pI[16];
    #pragma unroll
    for (int u = 0; u < 8; ++u) pF[wave][chb + u] = a[u];
    if (lane == 0) { pL[wave] = Lacc; pI[wave] = inv; }
    __syncthreads();
    if (tid < 512) {
        float f = 0.f;
        #pragma unroll
        for (int w = 0; w < 16; ++w) f += pF[w][tid];
        Fb[(size_t)s * CDIM + tid] = f2bf(f);
    }
    if (tid == 0) {
        float cnt = (float)(end - start);
        float Ls = 0.f; int ninv = 0;
        #pragma unroll
        for (int w = 0; w < 16; ++w) { Ls += pL[w]; ninv += pI[w]; }
        realn[s] = cnt - (float)ninv;
        Lout[s] = Ls + __expf(lsc[0]) * cnt;   // each lse = sf + log(sum)
    }
}

// ---- pooled[s,m] = (sf*Fb[s].capb[m] - L[s]) * (1/real or 0); 64x64 bf16 MFMA
//      NO LDS, NO BARRIERS: fragments loaded direct from row-major Fb/capb
//      (both 1 MB, L2-resident). ----
__global__ __launch_bounds__(256) void pooled_gemm(
    const u16* __restrict__ Fb, const u16* __restrict__ capb,
    const float* __restrict__ Lout, const float* __restrict__ realn,
    const float* __restrict__ lsc, float* __restrict__ out) {
    const int tid  = threadIdx.x;
    const int wave = tid >> 6;
    const int lane = tid & 63;
    const int col0 = blockIdx.x * 64;   // captions
    const int row0 = blockIdx.y * 64;   // segments
    const int wm = (wave >> 1) * 32;
    const int wn = (wave & 1) * 32;
    const float sf = __expf(lsc[0]);
    f32x4 acc[2][2] = {};
    const int mrow = lane & 15;
    const int quad = lane >> 4;
    // fragment for 16x16x32 bf16: lane (mrow,quad) holds row[k0+quad*8 .. +8]
    const u16* gA = Fb   + (size_t)(row0 + wm + mrow) * CDIM + quad * 8;
    const u16* gB = capb + (size_t)(col0 + wn + mrow) * CDIM + quad * 8;
    #pragma unroll
    for (int k0 = 0; k0 < CDIM; k0 += 32) {
        short8 af[2], bfr[2];
        #pragma unroll
        for (int i = 0; i < 2; ++i)
            af[i]  = *(const short8*)(gA + (size_t)(i * 16) * CDIM + k0);
        #pragma unroll
        for (int j = 0; j < 2; ++j)
            bfr[j] = *(const short8*)(gB + (size_t)(j * 16) * CDIM + k0);
        #pragma unroll
        for (int i = 0; i < 2; ++i)
            #pragma unroll
            for (int j = 0; j < 2; ++j)
                acc[i][j] = __builtin_amdgcn_mfma_f32_16x16x32_bf16(
                    af[i], bfr[j], acc[i][j], 0, 0, 0);
    }
    #pragma unroll
    for (int i = 0; i < 2; ++i) {
        #pragma unroll
        for (int r = 0; r < 4; ++r) {
            int s = row0 + wm + i * 16 + quad * 4 + r;
            float rn = realn[s];
            float dn = rn > 0.f ? 1.0f / rn : 0.0f;
            float L = Lout[s];
            #pragma unroll
            for (int j = 0; j < 2; ++j) {
                int mc = col0 + wn + j * 16 + mrow;
                out[(size_t)s * MCAP + mc] = (sf * acc[i][j][r] - L) * dn;
            }
        }
    }
    if (col0 == 0 && tid < 64) {
        int s = row0 + tid;
        float rv = realn[s];
        out[MCAP * MCAP + s] = rv;
        out[MCAP * MCAP + MCAP + s] = (rv > 0.f) ? 1.0f : 0.0f;
    }
}

extern "C" void kernel_launch(void* const* d_in, const int* in_sizes, int n_in,
                              void* d_out, int out_size, void* d_ws, size_t ws_size,
                              hipStream_t stream) {
    const float* adapter = (const float*)d_in[0];
    const float* cap     = (const float*)d_in[1];
    const float* lsc     = (const float*)d_in[2];
    const int*   v2p     = (const int*)d_in[3];
    const int*   oidx    = (const int*)d_in[4];
    const int*   ctpm    = (const int*)d_in[5];
    const int*   seg     = (const int*)d_in[6];
    float* out = (float*)d_out;

    char* ws = (char*)d_ws;
    u8*       feats8  = (u8*)(ws);                                // 67,108,864 B
    u16*      capb    = (u16*)(ws + 67108864);                    //  1,048,576 B
    u8*       Bswz    = (u8*)(ws + 68157440);                     //    524,288 B
    float*    lse_sum = (float*)(ws + 68681728);                  //    524,288 B
    int*      ptom    = (int*)(ws + 69206016);                    //    655,360 B
    unsigned* rows    = (unsigned*)(ws + 69861376);               //  1,048,576 B
    u16*      Fb      = (u16*)(ws + 70909952);                    //  1,048,576 B
    float*    Lout    = (float*)(ws + 71958528);                  //      4,096 B
    float*    realn   = (float*)(ws + 71962624);                  //      4,096 B

    hipMemsetAsync(ptom, 0xFF, (size_t)PORIG * 4, stream);        // -1

    gather_prep<<<33920, 256, 0, stream>>>(adapter, v2p, cap, oidx,
                                           feats8, capb, Bswz, ptom, lse_sum);
    lse_gemm<<<2048 + TLEN / 256, 256, 0, stream>>>(feats8, Bswz, lsc, lse_sum,
                                                    ctpm, ptom, rows);
    seg_reduce<<<MCAP, 1024, 0, stream>>>(feats8, lse_sum, rows, seg, lsc, Fb, Lout, realn);
    pooled_gemm<<<dim3(MCAP / 64, MCAP / 64), 256, 0, stream>>>(Fb, capb, Lout, realn, lsc, out);
}